// Round 6
// baseline (197.630 us; speedup 1.0000x reference)
//
#include <hip/hip_runtime.h>

namespace {

constexpr float FF[12] = {0.0144f, 0.0272f, 0.0526f, 0.0972f, 0.193f, 0.63f,
                          -0.63f, -0.193f, -0.0972f, -0.0526f, -0.0272f, -0.0144f};
constexpr float SQ2   = 1.41421356237309515f;
constexpr float NISQ2 = -0.70710678118654752f;

// Horizontal 12-tap correlation on one LDS row (float4-grouped), periodic width W4*4.
template <int O, int W4>
__device__ __forceinline__ float4 hconv(const float4* R4, int row4, int j4) {
  float r[20];
#pragma unroll
  for (int d = 0; d < 5; ++d) {
    float4 t = R4[row4 + ((j4 + d - 2) & (W4 - 1))];
    r[4 * d + 0] = t.x; r[4 * d + 1] = t.y; r[4 * d + 2] = t.z; r[4 * d + 3] = t.w;
  }
  float4 o = make_float4(0.f, 0.f, 0.f, 0.f);
#pragma unroll
  for (int a = 0; a < 12; ++a) {
    const float fa = FF[a];
    o.x += fa * r[8 + 0 + a - O];
    o.y += fa * r[8 + 1 + a - O];
    o.z += fa * r[8 + 2 + a - O];
    o.w += fa * r[8 + 3 + a - O];
  }
  return o;
}

// Streaming vertical conv, stage 1 (plain periodic, 128 rows x 32 groups):
// one thread produces 4 CONSECUTIVE rows (i0..i0+3) of column-group j4,
// reading each needed row ONCE (15 reads for 4 outputs vs 48 before).
// acc[k] fully static-indexed (unrolled) -> stays in VGPRs.
template <int O>
__device__ __forceinline__ void vconv4_s1(const float4* __restrict__ S4,
                                          int i0, int j4, float4 acc[4]) {
#pragma unroll
  for (int k = 0; k < 4; ++k) acc[k] = make_float4(0.f, 0.f, 0.f, 0.f);
#pragma unroll
  for (int rr = 0; rr < 15; ++rr) {
    float4 v = S4[((i0 + rr - O) & 127) * 32 + j4];
#pragma unroll
    for (int k = 0; k < 4; ++k) {
      constexpr int dummy = 0; (void)dummy;
      int a = rr - k;                 // compile-time constant after unroll
      if (a >= 0 && a < 12) {
        const float fa = FF[a];
        acc[k].x += fa * v.x; acc[k].y += fa * v.y;
        acc[k].z += fa * v.z; acc[k].w += fa * v.w;
      }
    }
  }
}

// Streaming vertical conv, stage 2 (qper_col rows, 128 rows x 64 groups;
// out-of-range rows wrap with column+128 == group XOR 32): one thread
// produces 8 consecutive rows, 19 reads for 8 outputs (vs 96 before).
template <int O>
__device__ __forceinline__ void vconv8_s2(const float4* __restrict__ S4,
                                          int i0, int j4, float4 acc[8]) {
#pragma unroll
  for (int k = 0; k < 8; ++k) acc[k] = make_float4(0.f, 0.f, 0.f, 0.f);
#pragma unroll
  for (int rr = 0; rr < 19; ++rr) {
    int r = i0 + rr - O;
    int idx = ((unsigned)r < 128u) ? (r * 64 + j4) : ((r & 127) * 64 + (j4 ^ 32));
    float4 v = S4[idx];
#pragma unroll
    for (int k = 0; k < 8; ++k) {
      int a = rr - k;                 // compile-time constant after unroll
      if (a >= 0 && a < 12) {
        const float fa = FF[a];
        acc[k].x += fa * v.x; acc[k].y += fa * v.y;
        acc[k].z += fa * v.z; acc[k].w += fa * v.w;
      }
    }
  }
}

// qprec '2c' scalar gather: x[i,jo] from p1 (bufA) / p0 (bufB), both 128x128.
__device__ __forceinline__ float qp2c(const float* __restrict__ bufA,
                                      const float* __restrict__ bufB,
                                      int i, int jo) {
  int J = (i + jo) & 255;
  int c = J >> 1;
  return (J & 1) ? bufA[((i - 1 - c) & 127) * 128 + c]
                 : bufB[((i - c) & 127) * 128 + c];
}

// Stage-1 core: fbrec filter chain for one 128x128 channel pair.
// On exit: A = p1, B = p0 (both 128x128), with a trailing barrier.
// Peak live registers: acc[4]+v = 20 floats (vconv) / pv[4]+hconv window
// = 44 (step 5, unchanged from the proven round-5 code).
__device__ __forceinline__ void s1_core(const float4* __restrict__ Y04,
                                        const float4* __restrict__ Y14,
                                        float4* __restrict__ A4,
                                        float4* __restrict__ B4, int tid) {
  const int rc4 = tid >> 5;        // row-chunk 0..31 (4 rows each)
  const int j4s = tid & 31;        // column group 0..31
  const int i0s = rc4 * 4;

  // 1. load Y0 plane -> A
#pragma unroll
  for (int k = 0; k < 4; ++k) A4[tid + k * 1024] = Y04[tid + k * 1024];
  __syncthreads();

  // 2. B = vert conv offset-5 of Y0 (A -> B, no in-place hazard)
  {
    float4 acc[4];
    vconv4_s1<5>(A4, i0s, j4s, acc);
#pragma unroll
    for (int k = 0; k < 4; ++k) B4[(i0s + k) * 32 + j4s] = acc[k];
  }
  __syncthreads();

  // 3. A = p1 = -1/sqrt2 * (Y1 + horz conv offset-5 of B)
#pragma unroll
  for (int k = 0; k < 4; ++k) {
    int g = tid + k * 1024;
    int i = g >> 5, j4 = g & 31;
    float4 h = hconv<5, 32>(B4, i * 32, j4);
    float4 yv = Y14[g];
    A4[g] = make_float4(NISQ2 * (yv.x + h.x), NISQ2 * (yv.y + h.y),
                        NISQ2 * (yv.z + h.z), NISQ2 * (yv.w + h.w));
  }
  __syncthreads();

  // 4. B = vert conv offset-6 of p1 (A -> B)
  {
    float4 acc[4];
    vconv4_s1<6>(A4, i0s, j4s, acc);
#pragma unroll
    for (int k = 0; k < 4; ++k) B4[(i0s + k) * 32 + j4s] = acc[k];
  }
  __syncthreads();

  // 5. B = p0 = sqrt2*Y0 + horz conv offset-6 of B (reg-staged; Y0 from L2)
  float4 pv[4];
#pragma unroll
  for (int k = 0; k < 4; ++k) {
    int g = tid + k * 1024;
    int i = g >> 5, j4 = g & 31;
    float4 h = hconv<6, 32>(B4, i * 32, j4);
    float4 yv = Y04[g];
    pv[k] = make_float4(SQ2 * yv.x + h.x, SQ2 * yv.y + h.y,
                        SQ2 * yv.z + h.z, SQ2 * yv.w + h.w);
  }
  __syncthreads();
#pragma unroll
  for (int k = 0; k < 4; ++k) B4[tid + k * 1024] = pv[k];
  __syncthreads();
}

}  // namespace

// Fused, 64-VGPR-honest: one block per output plane (b,c).  Large cross-phase
// state rides the HBM workspace via SAME-LANE write->read round trips.  Max
// register live set ~36 floats (proven scratch-free at the toolchain's hard
// 64-VGPR cap; rounds 1-4 showed every >40-float design gets alloca-demoted
// to scratch, immune to launch_bounds / waves_per_eu).  This round: streaming
// multi-row vertical convs cut vconv LDS reads 3.2x (s1) / 5x (s2) — the
// dominant modeled cost (~31 us of LDS-serial cycles at ds_read_b128 ~12cyc).
__global__ __launch_bounds__(1024) void fused_kernel(
    const float* __restrict__ y0, const float* __restrict__ y1,
    const float* __restrict__ y2, const float* __restrict__ y3,
    float* __restrict__ out, float* __restrict__ ws) {
  __shared__ float buf[32768];  // union: s1 {A,B} 64KiB each | s2 plane 128KiB
  float* bufA = buf;
  float* bufB = buf + 16384;
  float4* A4 = reinterpret_cast<float4*>(bufA);
  float4* B4 = reinterpret_cast<float4*>(bufB);
  float4* X4 = reinterpret_cast<float4*>(buf);

  const int q = blockIdx.x;  // 0..255 = b*32 + c
  const int tid = threadIdx.x;
  const size_t sub4 = (size_t)q * 4096;  // input plane offset in float4

  const float4* Y0a = reinterpret_cast<const float4*>(y2) + sub4;  // x1 inputs
  const float4* Y1a = reinterpret_cast<const float4*>(y3) + sub4;
  const float4* Y0b = reinterpret_cast<const float4*>(y1) + sub4;  // x0 inputs
  const float4* Y1b = reinterpret_cast<const float4*>(y0) + sub4;

  // Per-block ws slot: 65536 floats (x0 plane then x1 plane, 128 KiB each).
  float4* wsX0 = reinterpret_cast<float4*>(ws) + (size_t)q * 16384;
  float4* wsX1 = wsX0 + 8192;

  // ---------------- part A: x1 = fbrec(y2,y3) -> ws ----------------
  s1_core(Y0a, Y1a, A4, B4, tid);
  // qprec '2c' permute, gathered from LDS, written coalesced to ws.
#pragma unroll
  for (int k = 0; k < 8; ++k) {
    int t = tid + k * 1024;
    int i = t >> 6;
    int jb = (t & 63) << 2;
    float tmp[4];
#pragma unroll
    for (int m = 0; m < 4; ++m) tmp[m] = qp2c(bufA, bufB, i, jb + m);
    wsX1[t] = make_float4(tmp[0], tmp[1], tmp[2], tmp[3]);
  }
  __syncthreads();  // permute LDS reads done before part B overwrites A/B

  // ---------------- part B: x0 = fbrec(y1,y0) -> LDS plane + ws ----------------
  s1_core(Y0b, Y1b, A4, B4, tid);
  float4 g8[8];
#pragma unroll
  for (int k = 0; k < 8; ++k) {
    int t = tid + k * 1024;
    int i = t >> 6;
    int jb = (t & 63) << 2;
    float tmp[4];
#pragma unroll
    for (int m = 0; m < 4; ++m) tmp[m] = qp2c(bufA, bufB, i, jb + m);
    g8[k] = make_float4(tmp[0], tmp[1], tmp[2], tmp[3]);
  }
  __syncthreads();  // gather reads done; safe to overwrite the union buffer
#pragma unroll
  for (int k = 0; k < 8; ++k) {
    int t = tid + k * 1024;
    X4[t] = g8[k];     // stage-2 phase-1 content, no ws read needed
    wsX0[t] = g8[k];   // parked copy for the phase-5 re-read (same lane)
  }
  __syncthreads();

  // ---------------- stage 2: fbrec(x0, x1, '1r', 'qper_col') ----------------
  float* op = out + (size_t)q * 65536;
  const int rc8 = tid >> 6;        // row-chunk 0..15 (8 rows each)
  const int j4d = tid & 63;        // column group 0..63
  const int i0d = rc8 * 8;

  // 2. vert conv offset-5 (qper rows), streaming 8-row, in-place via barrier
  {
    float4 acc[8];
    vconv8_s2<5>(X4, i0d, j4d, acc);
    __syncthreads();
#pragma unroll
    for (int k = 0; k < 8; ++k) X4[(i0d + k) * 64 + j4d] = acc[k];
  }
  __syncthreads();

  // 3. p1 = -1/sqrt2 * (x1 + horz conv offset-5); x1 streamed from ws
  //    (same-lane re-read of part A's writes -> L2/L3-local)
  {
    float4 tv[8];
#pragma unroll
    for (int k = 0; k < 8; ++k) {
      int g = tid + k * 1024;
      int i = g >> 6, j4 = g & 63;
      float4 h = hconv<5, 64>(X4, i * 64, j4);
      float4 xv = wsX1[g];
      tv[k] = make_float4(NISQ2 * (xv.x + h.x), NISQ2 * (xv.y + h.y),
                          NISQ2 * (xv.z + h.z), NISQ2 * (xv.w + h.w));
    }
    __syncthreads();
#pragma unroll
    for (int k = 0; k < 8; ++k) X4[tid + k * 1024] = tv[k];
  }
  __syncthreads();

  // 3b. odd-I outputs while buf == p1: out[i,jo] = p1[r, (jo-1-r)&255],
  //     I=(i+jo)&255 odd, r=I>>1.  Scalar stride-2 stores (reads only; the
  //     sync after step-4 compute orders these vs. the next buf overwrite).
#pragma unroll
  for (int k = 0; k < 32; ++k) {
    int t = tid + k * 1024;  // 32768 odd positions
    int i = t >> 7;
    int u = t & 127;
    int jo = (u << 1) | ((i + 1) & 1);
    int r = ((i + jo) & 255) >> 1;
    int cc2 = (jo - 1 - r) & 255;
    op[i * 256 + jo] = buf[r * 256 + cc2];
  }

  // 4. vert conv offset-6 of p1 (qper rows), streaming 8-row, in-place
  {
    float4 acc[8];
    vconv8_s2<6>(X4, i0d, j4d, acc);
    __syncthreads();
#pragma unroll
    for (int k = 0; k < 8; ++k) X4[(i0d + k) * 64 + j4d] = acc[k];
  }
  __syncthreads();

  // 5. p0 = sqrt2*x0 + horz conv offset-6; x0 re-read from ws (same lane,
  //    written ~3 phases ago on this XCD -> mostly L2/L3)
  {
    float4 tv[8];
#pragma unroll
    for (int k = 0; k < 8; ++k) {
      int g = tid + k * 1024;
      int i = g >> 6, j4 = g & 63;
      float4 h = hconv<6, 64>(X4, i * 64, j4);
      float4 xv = wsX0[g];
      tv[k] = make_float4(SQ2 * xv.x + h.x, SQ2 * xv.y + h.y,
                          SQ2 * xv.z + h.z, SQ2 * xv.w + h.w);
    }
    __syncthreads();
#pragma unroll
    for (int k = 0; k < 8; ++k) X4[tid + k * 1024] = tv[k];
  }
  __syncthreads();

  // 6. even-I outputs: out[i,jo] = p0[r, (jo-r)&255], I even, r=I>>1.
#pragma unroll
  for (int k = 0; k < 32; ++k) {
    int t = tid + k * 1024;
    int i = t >> 7;
    int u = t & 127;
    int jo = (u << 1) | (i & 1);
    int r = ((i + jo) & 255) >> 1;
    int cc2 = (jo - r) & 255;
    op[i * 256 + jo] = buf[r * 256 + cc2];
  }
}

extern "C" void kernel_launch(void* const* d_in, const int* in_sizes, int n_in,
                              void* d_out, int out_size, void* d_ws, size_t ws_size,
                              hipStream_t stream) {
  const float* y0 = (const float*)d_in[0];
  const float* y1 = (const float*)d_in[1];
  const float* y2 = (const float*)d_in[2];
  const float* y3 = (const float*)d_in[3];
  float* outp = (float*)d_out;
  float* ws = (float*)d_ws;  // 64 MiB: per-block x0/x1 parking (same-lane round trips)

  fused_kernel<<<256, 1024, 0, stream>>>(y0, y1, y2, y3, outp, ws);
}